// Round 12
// baseline (190.845 us; speedup 1.0000x reference)
//
#include <hip/hip_runtime.h>
#include <hip/hip_fp16.h>

#define N_NODES 100000
#define N_EDGES 1600000
#define NPART 98           // partitions of 1024 nodes
#define CAP   20480        // bucket capacity

typedef _Float16 half8 __attribute__((ext_vector_type(8)));
typedef float f32x4 __attribute__((ext_vector_type(4)));

// ---------------- workspace layout (bytes) ----------------
#define WS_OFF   0          // int[N+1]
#define WS_PCUR  400016     // int[128]
#define WS_B     400528     // int[128]
#define WS_SJ    401040     // int[E]           (6.4 MB)
#define WS_WCOMB 6801040    // float[64*64]
#define WS_BCOMB 6817424    // float[64]
#define WS_PK    6817680    // _Float16[5*4096] (40 KB) B-frag packed weights
#define WS_QI8   6858640    // int8[N*64]       (6.4 MB)
#define WS_QS    13258640   // float[N]         (400 KB)
#define WS_BIN   19658640   // int[NPART*CAP] (8MB) OVERLAPS hm16 - disjoint lifetimes
#define WS_HM16  19658640   // _Float16[N*64]

__global__ void k_init0(int* pcur) {
    int t = threadIdx.x;
    if (t < NPART) pcur[t] = t * CAP;
}

// bin edges into 98 node-partition buckets; packed (i_local<<17)|j.
__global__ void __launch_bounds__(256) k_binc(const int* __restrict__ ei,
                                              const int* __restrict__ ej,
                                              int* pcur, int* __restrict__ binned) {
    __shared__ int cnt[NPART];
    __shared__ int base[NPART];
    int t = threadIdx.x;
    for (int q = t; q < NPART; q += 256) cnt[q] = 0;
    __syncthreads();

    int e0 = blockIdx.x * 2048 + t * 4;
    int e1 = e0 + 1024;
    bool v0 = e0 < N_EDGES, v1 = e1 < N_EDGES;
    int4 i0, j0, i1, j1;
    int p0[4], s0[4], p1[4], s1[4];
    if (v0) {
        i0 = *(const int4*)(ei + e0); j0 = *(const int4*)(ej + e0);
        p0[0] = i0.x >> 10; s0[0] = atomicAdd(&cnt[p0[0]], 1);
        p0[1] = i0.y >> 10; s0[1] = atomicAdd(&cnt[p0[1]], 1);
        p0[2] = i0.z >> 10; s0[2] = atomicAdd(&cnt[p0[2]], 1);
        p0[3] = i0.w >> 10; s0[3] = atomicAdd(&cnt[p0[3]], 1);
    }
    if (v1) {
        i1 = *(const int4*)(ei + e1); j1 = *(const int4*)(ej + e1);
        p1[0] = i1.x >> 10; s1[0] = atomicAdd(&cnt[p1[0]], 1);
        p1[1] = i1.y >> 10; s1[1] = atomicAdd(&cnt[p1[1]], 1);
        p1[2] = i1.z >> 10; s1[2] = atomicAdd(&cnt[p1[2]], 1);
        p1[3] = i1.w >> 10; s1[3] = atomicAdd(&cnt[p1[3]], 1);
    }
    __syncthreads();
    for (int q = t; q < NPART; q += 256)
        base[q] = cnt[q] ? atomicAdd(&pcur[q], cnt[q]) : 0;
    __syncthreads();
    if (v0) {
        int a;
        a = base[p0[0]] + s0[0]; if (a < (p0[0] + 1) * CAP) binned[a] = ((i0.x & 1023) << 17) | j0.x;
        a = base[p0[1]] + s0[1]; if (a < (p0[1] + 1) * CAP) binned[a] = ((i0.y & 1023) << 17) | j0.y;
        a = base[p0[2]] + s0[2]; if (a < (p0[2] + 1) * CAP) binned[a] = ((i0.z & 1023) << 17) | j0.z;
        a = base[p0[3]] + s0[3]; if (a < (p0[3] + 1) * CAP) binned[a] = ((i0.w & 1023) << 17) | j0.w;
    }
    if (v1) {
        int a;
        a = base[p1[0]] + s1[0]; if (a < (p1[0] + 1) * CAP) binned[a] = ((i1.x & 1023) << 17) | j1.x;
        a = base[p1[1]] + s1[1]; if (a < (p1[1] + 1) * CAP) binned[a] = ((i1.y & 1023) << 17) | j1.y;
        a = base[p1[2]] + s1[2]; if (a < (p1[2] + 1) * CAP) binned[a] = ((i1.z & 1023) << 17) | j1.z;
        a = base[p1[3]] + s1[3]; if (a < (p1[3] + 1) * CAP) binned[a] = ((i1.w & 1023) << 17) | j1.w;
    }
}

__global__ void k_scanB(const int* __restrict__ pcur, int* B) {
    __shared__ int s[128];
    int t = threadIdx.x;
    int c = 0;
    if (t < NPART) c = min(pcur[t] - t * CAP, CAP);
    s[t] = c;
    __syncthreads();
    for (int o = 1; o < 128; o <<= 1) {
        int a = (t >= o) ? s[t - o] : 0;
        __syncthreads();
        s[t] += a;
        __syncthreads();
    }
    if (t < NPART) B[t] = s[t] - c;
    if (t == NPART - 1) B[NPART] = s[t];
}

// per-partition counting sort: LDS histogram -> off[] + sj scatter. No global atomics.
__global__ void __launch_bounds__(256) k_fill3(const int* __restrict__ binned,
                                               const int* __restrict__ B,
                                               int* __restrict__ off,
                                               int* __restrict__ sj) {
    __shared__ int hist[1024];
    __shared__ int tsum[256];
    int p = blockIdx.x, t = threadIdx.x;
    int b0g = B[p];
    int cnt_p = B[p + 1] - b0g;
    const int* src = binned + p * CAP;

    #pragma unroll
    for (int q = 0; q < 4; ++q) hist[t * 4 + q] = 0;
    __syncthreads();
    for (int e = t; e < cnt_p; e += 256) atomicAdd(&hist[src[e] >> 17], 1);
    __syncthreads();

    int b0 = hist[t * 4], b1 = hist[t * 4 + 1], b2 = hist[t * 4 + 2], b3 = hist[t * 4 + 3];
    int c1 = b0, c2 = c1 + b1, c3 = c2 + b2, tot = c3 + b3;
    tsum[t] = tot;
    __syncthreads();
    for (int o = 1; o < 256; o <<= 1) {
        int a = (t >= o) ? tsum[t - o] : 0;
        __syncthreads();
        tsum[t] += a;
        __syncthreads();
    }
    int tex = tsum[t] - tot;
    hist[t * 4]     = tex;
    hist[t * 4 + 1] = tex + c1;
    hist[t * 4 + 2] = tex + c2;
    hist[t * 4 + 3] = tex + c3;
    __syncthreads();

    int lo = p * 1024;
    #pragma unroll
    for (int q = 0; q < 4; ++q) {
        int n = t * 4 + q, g = lo + n;
        if (g < N_NODES) off[g] = b0g + hist[n];
    }
    if (p == NPART - 1 && t == 0) off[N_NODES] = B[NPART];
    __syncthreads();

    for (int e = t; e < cnt_p; e += 256) {
        int v = src[e];
        int slot = atomicAdd(&hist[v >> 17], 1);
        sj[b0g + slot] = v & 0x1FFFF;
    }
}

__global__ void k_wcomb(const float* __restrict__ mw2, const float* __restrict__ mb2,
                        const float* __restrict__ aw1, float* wcomb, float* bcomb) {
    int o = blockIdx.x * blockDim.x + threadIdx.x;
    if (o < 64 * 64) {
        int c = o >> 6, k = o & 63;
        float s = 0.f;
        #pragma unroll 8
        for (int a = 0; a < 64; ++a) s += mw2[c * 64 + a] * aw1[(64 + a) * 64 + k];
        wcomb[o] = s;
    } else if (o < 64 * 64 + 64) {
        int k = o - 64 * 64;
        float s = 0.f;
        #pragma unroll 8
        for (int a = 0; a < 64; ++a) s += mb2[a] * aw1[(64 + a) * 64 + k];
        bcomb[k] = s;
    }
}

// Pack 5 weight matrices into MFMA B-fragment order.
__global__ void k_wpack(const float* __restrict__ mw1, const float* __restrict__ aw1,
                        const float* __restrict__ wcomb, const float* __restrict__ aw2,
                        _Float16* __restrict__ pk) {
    int mat = blockIdx.x;
    const float* src = (mat == 0) ? mw1 : (mat == 1) ? (mw1 + 4096)
                     : (mat == 2) ? aw1 : (mat == 3) ? wcomb : aw2;
    _Float16* dst = pk + mat * 4096;
    for (int t = threadIdx.x; t < 4096; t += 256) {
        int b_ = t & 7, l = (t >> 3) & 63, z = t >> 9;
        int kg = z & 1, nt = z >> 1;
        int k = kg * 32 + ((l >> 4) << 3) + b_;
        int n = nt * 16 + (l & 15);
        dst[t] = (_Float16)src[k * 64 + n];
    }
}

// ---- MFMA helpers ----
__device__ __forceinline__ half8 afrag_f32(const float* src, int row, int kg, int l) {
    const float* p = src + (size_t)row * 64 + kg * 32 + ((l >> 4) << 3);
    float4 u = *(const float4*)p;
    float4 v = *(const float4*)(p + 4);
    half8 h;
    h[0] = (_Float16)u.x; h[1] = (_Float16)u.y; h[2] = (_Float16)u.z; h[3] = (_Float16)u.w;
    h[4] = (_Float16)v.x; h[5] = (_Float16)v.y; h[6] = (_Float16)v.z; h[7] = (_Float16)v.w;
    return h;
}

// Fused: P' = x@W1a + mb1 - pos@W1p (fp32 -> d_out temp)
//        Q' = x@W1b       + pos@W1p -> int8 row-quantized + fp32 scale
__global__ void __launch_bounds__(256) k_pre(const float* __restrict__ x,
                                             const float* __restrict__ pos,
                                             const float* __restrict__ mw1,
                                             const float* __restrict__ mb1,
                                             const _Float16* __restrict__ pk,
                                             float* __restrict__ P,
                                             signed char* __restrict__ Qi8,
                                             float* __restrict__ Qs) {
    int w = threadIdx.x >> 6, l = threadIdx.x & 63;
    int m0 = blockIdx.x * 128 + w * 32;

    half8 a[2][2];
    #pragma unroll
    for (int s = 0; s < 2; ++s)
        #pragma unroll
        for (int kg = 0; kg < 2; ++kg) {
            int row = m0 + s * 16 + (l & 15);
            if (row >= N_NODES) row = N_NODES - 1;
            a[s][kg] = afrag_f32(x, row, kg, l);
        }

    f32x4 z = {0.f, 0.f, 0.f, 0.f};
    f32x4 accP[2][4], accQ[2][4];
    #pragma unroll
    for (int s = 0; s < 2; ++s)
        #pragma unroll
        for (int nt = 0; nt < 4; ++nt) { accP[s][nt] = z; accQ[s][nt] = z; }

    #pragma unroll
    for (int nt = 0; nt < 4; ++nt)
        #pragma unroll
        for (int kg = 0; kg < 2; ++kg) {
            half8 b = *(const half8*)(pk + ((nt * 2 + kg) * 64 + l) * 8);
            accP[0][nt] = __builtin_amdgcn_mfma_f32_16x16x32_f16(a[0][kg], b, accP[0][nt], 0, 0, 0);
            accP[1][nt] = __builtin_amdgcn_mfma_f32_16x16x32_f16(a[1][kg], b, accP[1][nt], 0, 0, 0);
        }
    const _Float16* pkb = pk + 4096;
    #pragma unroll
    for (int nt = 0; nt < 4; ++nt)
        #pragma unroll
        for (int kg = 0; kg < 2; ++kg) {
            half8 b = *(const half8*)(pkb + ((nt * 2 + kg) * 64 + l) * 8);
            accQ[0][nt] = __builtin_amdgcn_mfma_f32_16x16x32_f16(a[0][kg], b, accQ[0][nt], 0, 0, 0);
            accQ[1][nt] = __builtin_amdgcn_mfma_f32_16x16x32_f16(a[1][kg], b, accQ[1][nt], 0, 0, 0);
        }

    int col = l & 15;
    float wx[4], wy[4], wz[4], bb[4];
    #pragma unroll
    for (int nt = 0; nt < 4; ++nt) {
        int n = nt * 16 + col;
        wx[nt] = mw1[128 * 64 + n];
        wy[nt] = mw1[129 * 64 + n];
        wz[nt] = mw1[130 * 64 + n];
        bb[nt] = mb1[n];
    }
    #pragma unroll
    for (int s = 0; s < 2; ++s)
        #pragma unroll
        for (int r = 0; r < 4; ++r) {
            int m = m0 + s * 16 + ((l >> 4) << 2) + r;
            if (m >= N_NODES) continue;   // uniform across the 16-lane group
            float px = pos[3 * m], py = pos[3 * m + 1], pz = pos[3 * m + 2];
            float qn[4];
            #pragma unroll
            for (int nt = 0; nt < 4; ++nt) {
                int n = nt * 16 + col;
                float pd = px * wx[nt] + py * wy[nt] + pz * wz[nt];
                P[(size_t)m * 64 + n] = accP[s][nt][r] + bb[nt] - pd;
                qn[nt] = accQ[s][nt][r] + pd;
            }
            float mx = fmaxf(fmaxf(fabsf(qn[0]), fabsf(qn[1])),
                             fmaxf(fabsf(qn[2]), fabsf(qn[3])));
            #pragma unroll
            for (int d = 1; d < 16; d <<= 1) mx = fmaxf(mx, __shfl_xor(mx, d, 64));
            float inv = (mx > 0.f) ? 127.f / mx : 0.f;
            #pragma unroll
            for (int nt = 0; nt < 4; ++nt)
                Qi8[(size_t)m * 64 + nt * 16 + col] = (signed char)(int)rintf(qn[nt] * inv);
            if (col == 0) Qs[m] = mx * (1.f / 127.f);
        }
}

// Edge aggregation: hmean = mean(relu(P'_i + Qi8[j]*Qs[j])) -> fp16.
// Mask-free: full batches of 8 with NAMED registers (true 8-deep MLP),
// scalar-path tail (j uniform -> s_load). launch_bounds(256,4) for VGPR room.
__global__ void __launch_bounds__(256, 4) k_c1(const signed char* __restrict__ Qi8,
                                               const float* __restrict__ Qs,
                                               const int* __restrict__ off,
                                               const int* __restrict__ sj,
                                               const float* __restrict__ Phm,
                                               _Float16* __restrict__ hm16) {
    int wave = threadIdx.x >> 6, lane = threadIdx.x & 63;
    int node = blockIdx.x * 4 + wave;
    if (node >= N_NODES) return;
    float Pv = Phm[(size_t)node * 64 + lane];
    int o0 = off[node], o1 = off[node + 1];
    int dg = o1 - o0;
    float acc = 0.f;
    int e = o0;
    for (; e + 8 <= o1; e += 8) {
        int jv = sj[e + (lane & 7)];
        int j0 = __builtin_amdgcn_readlane(jv, 0);
        int j1 = __builtin_amdgcn_readlane(jv, 1);
        int j2 = __builtin_amdgcn_readlane(jv, 2);
        int j3 = __builtin_amdgcn_readlane(jv, 3);
        int j4 = __builtin_amdgcn_readlane(jv, 4);
        int j5 = __builtin_amdgcn_readlane(jv, 5);
        int j6 = __builtin_amdgcn_readlane(jv, 6);
        int j7 = __builtin_amdgcn_readlane(jv, 7);
        float b0 = (float)Qi8[j0 * 64 + lane];
        float b1 = (float)Qi8[j1 * 64 + lane];
        float b2 = (float)Qi8[j2 * 64 + lane];
        float b3 = (float)Qi8[j3 * 64 + lane];
        float b4 = (float)Qi8[j4 * 64 + lane];
        float b5 = (float)Qi8[j5 * 64 + lane];
        float b6 = (float)Qi8[j6 * 64 + lane];
        float b7 = (float)Qi8[j7 * 64 + lane];
        float s0 = Qs[j0], s1 = Qs[j1], s2 = Qs[j2], s3 = Qs[j3];
        float s4 = Qs[j4], s5 = Qs[j5], s6 = Qs[j6], s7 = Qs[j7];
        acc += fmaxf(fmaf(b0, s0, Pv), 0.f);
        acc += fmaxf(fmaf(b1, s1, Pv), 0.f);
        acc += fmaxf(fmaf(b2, s2, Pv), 0.f);
        acc += fmaxf(fmaf(b3, s3, Pv), 0.f);
        acc += fmaxf(fmaf(b4, s4, Pv), 0.f);
        acc += fmaxf(fmaf(b5, s5, Pv), 0.f);
        acc += fmaxf(fmaf(b6, s6, Pv), 0.f);
        acc += fmaxf(fmaf(b7, s7, Pv), 0.f);
    }
    for (; e < o1; ++e) {
        int j = sj[e];                          // uniform -> scalar load
        float s = Qs[j];                        // uniform -> scalar load
        float b = (float)Qi8[j * 64 + lane];
        acc += fmaxf(fmaf(b, s, Pv), 0.f);
    }
    hm16[(size_t)node * 64 + lane] = (_Float16)((dg > 0) ? acc / (float)dg : 0.f);
}

// out = relu(x@aw1t + hm@wcomb + ab1 + [deg>0]*bcomb) @ aw2 + ab2   (MFMA)
__global__ void __launch_bounds__(256) k_c2(const float* __restrict__ x,
                                            const _Float16* __restrict__ hm16,
                                            const _Float16* __restrict__ pk,
                                            const float* __restrict__ ab1,
                                            const float* __restrict__ bcomb,
                                            const float* __restrict__ ab2,
                                            const int* __restrict__ off,
                                            float* __restrict__ out) {
    __shared__ _Float16 lsh[4][2][16][64];
    int w = threadIdx.x >> 6, l = threadIdx.x & 63;
    int m0 = blockIdx.x * 128 + w * 32;
    int col = l & 15;

    f32x4 z = {0.f, 0.f, 0.f, 0.f};
    f32x4 acc[2][4];
    #pragma unroll
    for (int s = 0; s < 2; ++s)
        #pragma unroll
        for (int nt = 0; nt < 4; ++nt) acc[s][nt] = z;

    {
        half8 a[2][2];
        #pragma unroll
        for (int s = 0; s < 2; ++s)
            #pragma unroll
            for (int kg = 0; kg < 2; ++kg) {
                int row = m0 + s * 16 + (l & 15);
                if (row >= N_NODES) row = N_NODES - 1;
                a[s][kg] = afrag_f32(x, row, kg, l);
            }
        const _Float16* pk1 = pk + 2 * 4096;
        #pragma unroll
        for (int nt = 0; nt < 4; ++nt)
            #pragma unroll
            for (int kg = 0; kg < 2; ++kg) {
                half8 b = *(const half8*)(pk1 + ((nt * 2 + kg) * 64 + l) * 8);
                acc[0][nt] = __builtin_amdgcn_mfma_f32_16x16x32_f16(a[0][kg], b, acc[0][nt], 0, 0, 0);
                acc[1][nt] = __builtin_amdgcn_mfma_f32_16x16x32_f16(a[1][kg], b, acc[1][nt], 0, 0, 0);
            }
    }
    {
        half8 a[2][2];
        #pragma unroll
        for (int s = 0; s < 2; ++s)
            #pragma unroll
            for (int kg = 0; kg < 2; ++kg) {
                int row = m0 + s * 16 + (l & 15);
                if (row >= N_NODES) row = N_NODES - 1;
                a[s][kg] = *(const half8*)(hm16 + (size_t)row * 64 + kg * 32 + ((l >> 4) << 3));
            }
        const _Float16* pk2 = pk + 3 * 4096;
        #pragma unroll
        for (int nt = 0; nt < 4; ++nt)
            #pragma unroll
            for (int kg = 0; kg < 2; ++kg) {
                half8 b = *(const half8*)(pk2 + ((nt * 2 + kg) * 64 + l) * 8);
                acc[0][nt] = __builtin_amdgcn_mfma_f32_16x16x32_f16(a[0][kg], b, acc[0][nt], 0, 0, 0);
                acc[1][nt] = __builtin_amdgcn_mfma_f32_16x16x32_f16(a[1][kg], b, acc[1][nt], 0, 0, 0);
            }
    }

    float a1n[4], bcn[4];
    #pragma unroll
    for (int nt = 0; nt < 4; ++nt) {
        int n = nt * 16 + col;
        a1n[nt] = ab1[n];
        bcn[nt] = bcomb[n];
    }
    #pragma unroll
    for (int s = 0; s < 2; ++s)
        #pragma unroll
        for (int r = 0; r < 4; ++r) {
            int row = ((l >> 4) << 2) + r;
            int m = m0 + s * 16 + row;
            int dg = (m < N_NODES) ? (off[m + 1] - off[m]) : 0;
            #pragma unroll
            for (int nt = 0; nt < 4; ++nt) {
                int n = nt * 16 + col;
                float v = acc[s][nt][r] + a1n[nt] + ((dg > 0) ? bcn[nt] : 0.f);
                v = fmaxf(v, 0.f);
                lsh[w][s][row][n ^ ((row & 7) << 3)] = (_Float16)v;
            }
        }
    __syncthreads();

    f32x4 acc2[2][4];
    #pragma unroll
    for (int s = 0; s < 2; ++s)
        #pragma unroll
        for (int nt = 0; nt < 4; ++nt) acc2[s][nt] = z;
    {
        half8 a[2][2];
        #pragma unroll
        for (int s = 0; s < 2; ++s)
            #pragma unroll
            for (int kg = 0; kg < 2; ++kg) {
                int rr = l & 15;
                int c0 = (kg * 32 + ((l >> 4) << 3)) ^ ((rr & 7) << 3);
                a[s][kg] = *(const half8*)&lsh[w][s][rr][c0];
            }
        const _Float16* pk3 = pk + 4 * 4096;
        #pragma unroll
        for (int nt = 0; nt < 4; ++nt)
            #pragma unroll
            for (int kg = 0; kg < 2; ++kg) {
                half8 b = *(const half8*)(pk3 + ((nt * 2 + kg) * 64 + l) * 8);
                acc2[0][nt] = __builtin_amdgcn_mfma_f32_16x16x32_f16(a[0][kg], b, acc2[0][nt], 0, 0, 0);
                acc2[1][nt] = __builtin_amdgcn_mfma_f32_16x16x32_f16(a[1][kg], b, acc2[1][nt], 0, 0, 0);
            }
    }

    float a2n[4];
    #pragma unroll
    for (int nt = 0; nt < 4; ++nt) a2n[nt] = ab2[nt * 16 + col];
    #pragma unroll
    for (int s = 0; s < 2; ++s)
        #pragma unroll
        for (int r = 0; r < 4; ++r) {
            int m = m0 + s * 16 + ((l >> 4) << 2) + r;
            if (m >= N_NODES) continue;
            #pragma unroll
            for (int nt = 0; nt < 4; ++nt)
                out[(size_t)m * 64 + nt * 16 + col] = acc2[s][nt][r] + a2n[nt];
        }
}

extern "C" void kernel_launch(void* const* d_in, const int* in_sizes, int n_in,
                              void* d_out, int out_size, void* d_ws, size_t ws_size,
                              hipStream_t stream) {
    const float* x   = (const float*)d_in[0];
    const int*   ei  = (const int*)d_in[1];
    const int*   ej  = ((const int*)d_in[1]) + N_EDGES;
    const float* pos = (const float*)d_in[2];
    const float* mw1 = (const float*)d_in[3];
    const float* mb1 = (const float*)d_in[4];
    const float* mw2 = (const float*)d_in[5];
    const float* mb2 = (const float*)d_in[6];
    const float* aw1 = (const float*)d_in[7];
    const float* ab1 = (const float*)d_in[8];
    const float* aw2 = (const float*)d_in[9];
    const float* ab2 = (const float*)d_in[10];

    char* ws = (char*)d_ws;
    int*         off    = (int*)(ws + WS_OFF);
    int*         pcur   = (int*)(ws + WS_PCUR);
    int*         B      = (int*)(ws + WS_B);
    int*         sj     = (int*)(ws + WS_SJ);
    float*       wcomb  = (float*)(ws + WS_WCOMB);
    float*       bcomb  = (float*)(ws + WS_BCOMB);
    _Float16*    pk     = (_Float16*)(ws + WS_PK);
    signed char* Qi8    = (signed char*)(ws + WS_QI8);
    float*       Qs     = (float*)(ws + WS_QS);
    int*         binned = (int*)(ws + WS_BIN);
    _Float16*    hm16   = (_Float16*)(ws + WS_HM16);
    float*       out    = (float*)d_out;

    const int NBT = (N_NODES + 127) / 128;        // 782
    const int NBB = (N_EDGES + 2047) / 2048;      // 782
    hipLaunchKernelGGL(k_init0, dim3(1), dim3(128), 0, stream, pcur);
    hipLaunchKernelGGL(k_binc,  dim3(NBB), dim3(256), 0, stream, ei, ej, pcur, binned);
    hipLaunchKernelGGL(k_scanB, dim3(1), dim3(128), 0, stream, pcur, B);
    hipLaunchKernelGGL(k_fill3, dim3(NPART), dim3(256), 0, stream, binned, B, off, sj);
    hipLaunchKernelGGL(k_wcomb, dim3(17), dim3(256), 0, stream, mw2, mb2, aw1, wcomb, bcomb);
    hipLaunchKernelGGL(k_wpack, dim3(5), dim3(256), 0, stream, mw1, aw1, wcomb, aw2, pk);
    hipLaunchKernelGGL(k_pre,   dim3(NBT), dim3(256), 0, stream, x, pos, mw1, mb1, pk, out, Qi8, Qs);
    hipLaunchKernelGGL(k_c1,    dim3((N_NODES + 3) / 4), dim3(256), 0, stream,
                       Qi8, Qs, off, sj, out, hm16);
    hipLaunchKernelGGL(k_c2,    dim3(NBT), dim3(256), 0, stream,
                       x, hm16, pk, ab1, bcomb, ab2, off, out);
}

// Round 13
// 176.241 us; speedup vs baseline: 1.0829x; 1.0829x over previous
//
#include <hip/hip_runtime.h>
#include <hip/hip_fp16.h>

#define N_NODES 100000
#define N_EDGES 1600000
#define NPART 98           // partitions of 1024 nodes
#define CAP   20480        // bucket capacity
#define EB    8192         // edges per k_binc block

typedef _Float16 half8 __attribute__((ext_vector_type(8)));
typedef float f32x4 __attribute__((ext_vector_type(4)));

// ---------------- workspace layout (bytes) ----------------
#define WS_OFF   0          // int[N+1]
#define WS_PCUR  400016     // int[128]
#define WS_B     400528     // int[128]
#define WS_SJ    401040     // int[E]           (6.4 MB)
#define WS_WCOMB 6801040    // float[64*64]
#define WS_BCOMB 6817424    // float[64]
#define WS_PK    6817680    // _Float16[5*4096] (40 KB) B-frag packed weights
#define WS_QI8   6858640    // int8[N*64]       (6.4 MB)
#define WS_QS    13258640   // float[N]         (400 KB)
#define WS_BIN   19658640   // int[NPART*CAP] (8MB) OVERLAPS hm16 - disjoint lifetimes
#define WS_HM16  19658640   // _Float16[N*64]

__global__ void k_init0(int* pcur) {
    int t = threadIdx.x;
    if (t < NPART) pcur[t] = t * CAP;
}

// 3-phase bin: count -> reserve -> re-read (L2-hot) + scatter.
// 8192 edges/block => ~84 ints per bucket-run => few partial-line writes.
__global__ void __launch_bounds__(256) k_binc(const int* __restrict__ ei,
                                              const int* __restrict__ ej,
                                              int* pcur, int* __restrict__ binned) {
    __shared__ int cnt[NPART];
    __shared__ int wcur[NPART];
    int t = threadIdx.x;
    for (int q = t; q < NPART; q += 256) cnt[q] = 0;
    __syncthreads();
    int base_e = blockIdx.x * EB;
    #pragma unroll 2
    for (int it = 0; it < EB / 1024; ++it) {
        int e = base_e + it * 1024 + t * 4;
        if (e < N_EDGES) {
            int4 iv = *(const int4*)(ei + e);
            atomicAdd(&cnt[iv.x >> 10], 1);
            atomicAdd(&cnt[iv.y >> 10], 1);
            atomicAdd(&cnt[iv.z >> 10], 1);
            atomicAdd(&cnt[iv.w >> 10], 1);
        }
    }
    __syncthreads();
    for (int q = t; q < NPART; q += 256)
        wcur[q] = cnt[q] ? atomicAdd(&pcur[q], cnt[q]) : 0;
    __syncthreads();
    #pragma unroll 2
    for (int it = 0; it < EB / 1024; ++it) {
        int e = base_e + it * 1024 + t * 4;
        if (e < N_EDGES) {
            int4 iv = *(const int4*)(ei + e);
            int4 jv = *(const int4*)(ej + e);
            int a, p;
            p = iv.x >> 10; a = atomicAdd(&wcur[p], 1);
            if (a < (p + 1) * CAP) binned[a] = ((iv.x & 1023) << 17) | jv.x;
            p = iv.y >> 10; a = atomicAdd(&wcur[p], 1);
            if (a < (p + 1) * CAP) binned[a] = ((iv.y & 1023) << 17) | jv.y;
            p = iv.z >> 10; a = atomicAdd(&wcur[p], 1);
            if (a < (p + 1) * CAP) binned[a] = ((iv.z & 1023) << 17) | jv.z;
            p = iv.w >> 10; a = atomicAdd(&wcur[p], 1);
            if (a < (p + 1) * CAP) binned[a] = ((iv.w & 1023) << 17) | jv.w;
        }
    }
}

__global__ void k_scanB(const int* __restrict__ pcur, int* B) {
    __shared__ int s[128];
    int t = threadIdx.x;
    int c = 0;
    if (t < NPART) c = min(pcur[t] - t * CAP, CAP);
    s[t] = c;
    __syncthreads();
    for (int o = 1; o < 128; o <<= 1) {
        int a = (t >= o) ? s[t - o] : 0;
        __syncthreads();
        s[t] += a;
        __syncthreads();
    }
    if (t < NPART) B[t] = s[t] - c;
    if (t == NPART - 1) B[NPART] = s[t];
}

// per-partition counting sort: LDS histogram -> off[] + sj scatter. No global atomics.
__global__ void __launch_bounds__(256) k_fill3(const int* __restrict__ binned,
                                               const int* __restrict__ B,
                                               int* __restrict__ off,
                                               int* __restrict__ sj) {
    __shared__ int hist[1024];
    __shared__ int tsum[256];
    int p = blockIdx.x, t = threadIdx.x;
    int b0g = B[p];
    int cnt_p = B[p + 1] - b0g;
    const int* src = binned + p * CAP;

    #pragma unroll
    for (int q = 0; q < 4; ++q) hist[t * 4 + q] = 0;
    __syncthreads();
    for (int e = t; e < cnt_p; e += 256) atomicAdd(&hist[src[e] >> 17], 1);
    __syncthreads();

    int b0 = hist[t * 4], b1 = hist[t * 4 + 1], b2 = hist[t * 4 + 2], b3 = hist[t * 4 + 3];
    int c1 = b0, c2 = c1 + b1, c3 = c2 + b2, tot = c3 + b3;
    tsum[t] = tot;
    __syncthreads();
    for (int o = 1; o < 256; o <<= 1) {
        int a = (t >= o) ? tsum[t - o] : 0;
        __syncthreads();
        tsum[t] += a;
        __syncthreads();
    }
    int tex = tsum[t] - tot;
    hist[t * 4]     = tex;
    hist[t * 4 + 1] = tex + c1;
    hist[t * 4 + 2] = tex + c2;
    hist[t * 4 + 3] = tex + c3;
    __syncthreads();

    int lo = p * 1024;
    #pragma unroll
    for (int q = 0; q < 4; ++q) {
        int n = t * 4 + q, g = lo + n;
        if (g < N_NODES) off[g] = b0g + hist[n];
    }
    if (p == NPART - 1 && t == 0) off[N_NODES] = B[NPART];
    __syncthreads();

    for (int e = t; e < cnt_p; e += 256) {
        int v = src[e];
        int slot = atomicAdd(&hist[v >> 17], 1);
        sj[b0g + slot] = v & 0x1FFFF;
    }
}

__global__ void k_wcomb(const float* __restrict__ mw2, const float* __restrict__ mb2,
                        const float* __restrict__ aw1, float* wcomb, float* bcomb) {
    int o = blockIdx.x * blockDim.x + threadIdx.x;
    if (o < 64 * 64) {
        int c = o >> 6, k = o & 63;
        float s = 0.f;
        #pragma unroll 8
        for (int a = 0; a < 64; ++a) s += mw2[c * 64 + a] * aw1[(64 + a) * 64 + k];
        wcomb[o] = s;
    } else if (o < 64 * 64 + 64) {
        int k = o - 64 * 64;
        float s = 0.f;
        #pragma unroll 8
        for (int a = 0; a < 64; ++a) s += mb2[a] * aw1[(64 + a) * 64 + k];
        bcomb[k] = s;
    }
}

// Pack 5 weight matrices into MFMA B-fragment order.
__global__ void k_wpack(const float* __restrict__ mw1, const float* __restrict__ aw1,
                        const float* __restrict__ wcomb, const float* __restrict__ aw2,
                        _Float16* __restrict__ pk) {
    int mat = blockIdx.x;
    const float* src = (mat == 0) ? mw1 : (mat == 1) ? (mw1 + 4096)
                     : (mat == 2) ? aw1 : (mat == 3) ? wcomb : aw2;
    _Float16* dst = pk + mat * 4096;
    for (int t = threadIdx.x; t < 4096; t += 256) {
        int b_ = t & 7, l = (t >> 3) & 63, z = t >> 9;
        int kg = z & 1, nt = z >> 1;
        int k = kg * 32 + ((l >> 4) << 3) + b_;
        int n = nt * 16 + (l & 15);
        dst[t] = (_Float16)src[k * 64 + n];
    }
}

// ---- MFMA helpers ----
__device__ __forceinline__ half8 afrag_f32(const float* src, int row, int kg, int l) {
    const float* p = src + (size_t)row * 64 + kg * 32 + ((l >> 4) << 3);
    float4 u = *(const float4*)p;
    float4 v = *(const float4*)(p + 4);
    half8 h;
    h[0] = (_Float16)u.x; h[1] = (_Float16)u.y; h[2] = (_Float16)u.z; h[3] = (_Float16)u.w;
    h[4] = (_Float16)v.x; h[5] = (_Float16)v.y; h[6] = (_Float16)v.z; h[7] = (_Float16)v.w;
    return h;
}

// Fused: P' = x@W1a + mb1 - pos@W1p (fp32 -> d_out temp)
//        Q' = x@W1b       + pos@W1p -> int8 row-quantized + fp32 scale
__global__ void __launch_bounds__(256) k_pre(const float* __restrict__ x,
                                             const float* __restrict__ pos,
                                             const float* __restrict__ mw1,
                                             const float* __restrict__ mb1,
                                             const _Float16* __restrict__ pk,
                                             float* __restrict__ P,
                                             signed char* __restrict__ Qi8,
                                             float* __restrict__ Qs) {
    int w = threadIdx.x >> 6, l = threadIdx.x & 63;
    int m0 = blockIdx.x * 128 + w * 32;

    half8 a[2][2];
    #pragma unroll
    for (int s = 0; s < 2; ++s)
        #pragma unroll
        for (int kg = 0; kg < 2; ++kg) {
            int row = m0 + s * 16 + (l & 15);
            if (row >= N_NODES) row = N_NODES - 1;
            a[s][kg] = afrag_f32(x, row, kg, l);
        }

    f32x4 z = {0.f, 0.f, 0.f, 0.f};
    f32x4 accP[2][4], accQ[2][4];
    #pragma unroll
    for (int s = 0; s < 2; ++s)
        #pragma unroll
        for (int nt = 0; nt < 4; ++nt) { accP[s][nt] = z; accQ[s][nt] = z; }

    #pragma unroll
    for (int nt = 0; nt < 4; ++nt)
        #pragma unroll
        for (int kg = 0; kg < 2; ++kg) {
            half8 b = *(const half8*)(pk + ((nt * 2 + kg) * 64 + l) * 8);
            accP[0][nt] = __builtin_amdgcn_mfma_f32_16x16x32_f16(a[0][kg], b, accP[0][nt], 0, 0, 0);
            accP[1][nt] = __builtin_amdgcn_mfma_f32_16x16x32_f16(a[1][kg], b, accP[1][nt], 0, 0, 0);
        }
    const _Float16* pkb = pk + 4096;
    #pragma unroll
    for (int nt = 0; nt < 4; ++nt)
        #pragma unroll
        for (int kg = 0; kg < 2; ++kg) {
            half8 b = *(const half8*)(pkb + ((nt * 2 + kg) * 64 + l) * 8);
            accQ[0][nt] = __builtin_amdgcn_mfma_f32_16x16x32_f16(a[0][kg], b, accQ[0][nt], 0, 0, 0);
            accQ[1][nt] = __builtin_amdgcn_mfma_f32_16x16x32_f16(a[1][kg], b, accQ[1][nt], 0, 0, 0);
        }

    int col = l & 15;
    float wx[4], wy[4], wz[4], bb[4];
    #pragma unroll
    for (int nt = 0; nt < 4; ++nt) {
        int n = nt * 16 + col;
        wx[nt] = mw1[128 * 64 + n];
        wy[nt] = mw1[129 * 64 + n];
        wz[nt] = mw1[130 * 64 + n];
        bb[nt] = mb1[n];
    }
    #pragma unroll
    for (int s = 0; s < 2; ++s)
        #pragma unroll
        for (int r = 0; r < 4; ++r) {
            int m = m0 + s * 16 + ((l >> 4) << 2) + r;
            if (m >= N_NODES) continue;   // uniform across the 16-lane group
            float px = pos[3 * m], py = pos[3 * m + 1], pz = pos[3 * m + 2];
            float qn[4];
            #pragma unroll
            for (int nt = 0; nt < 4; ++nt) {
                int n = nt * 16 + col;
                float pd = px * wx[nt] + py * wy[nt] + pz * wz[nt];
                P[(size_t)m * 64 + n] = accP[s][nt][r] + bb[nt] - pd;
                qn[nt] = accQ[s][nt][r] + pd;
            }
            float mx = fmaxf(fmaxf(fabsf(qn[0]), fabsf(qn[1])),
                             fmaxf(fabsf(qn[2]), fabsf(qn[3])));
            #pragma unroll
            for (int d = 1; d < 16; d <<= 1) mx = fmaxf(mx, __shfl_xor(mx, d, 64));
            float inv = (mx > 0.f) ? 127.f / mx : 0.f;
            #pragma unroll
            for (int nt = 0; nt < 4; ++nt)
                Qi8[(size_t)m * 64 + nt * 16 + col] = (signed char)(int)rintf(qn[nt] * inv);
            if (col == 0) Qs[m] = mx * (1.f / 127.f);
        }
}

// Edge aggregation: TWO nodes per wave, interleaved 16-gather groups
// (32 loads in flight, two independent acc chains, better balance).
// N_NODES % 8 == 0 so node pairs are always in range.
__global__ void __launch_bounds__(256, 4) k_c1(const signed char* __restrict__ Qi8,
                                               const float* __restrict__ Qs,
                                               const int* __restrict__ off,
                                               const int* __restrict__ sj,
                                               const float* __restrict__ Phm,
                                               _Float16* __restrict__ hm16) {
    int wave = threadIdx.x >> 6, lane = threadIdx.x & 63;
    int n0 = blockIdx.x * 8 + wave * 2;
    float Pv0 = Phm[(size_t)n0 * 64 + lane];
    float Pv1 = Phm[(size_t)(n0 + 1) * 64 + lane];
    int oA = off[n0], oM = off[n0 + 1], oE = off[n0 + 2];
    int dgA = oM - oA, dgB = oE - oM;
    float accA = 0.f, accB = 0.f;
    int eA = oA, eB = oM;
    while (eA < oM || eB < oE) {
        int mA = min(64, oM - eA);
        int mB = min(64, oE - eB);
        int jvA = (lane < mA) ? sj[eA + lane] : 0;
        int jvB = (lane < mB) ? sj[eB + lane] : 0;
        for (int g = 0; g < 64; g += 16) {
            if (g >= mA && g >= mB) break;
            float vA[16], sA[16], vB[16], sB[16];
            if (g < mA) {
                #pragma unroll
                for (int cc = 0; cc < 16; ++cc) {
                    int jc = __builtin_amdgcn_readlane(jvA, g + cc);
                    sA[cc] = Qs[jc];
                    vA[cc] = (float)Qi8[jc * 64 + lane];
                }
            }
            if (g < mB) {
                #pragma unroll
                for (int cc = 0; cc < 16; ++cc) {
                    int jc = __builtin_amdgcn_readlane(jvB, g + cc);
                    sB[cc] = Qs[jc];
                    vB[cc] = (float)Qi8[jc * 64 + lane];
                }
            }
            if (g < mA) {
                #pragma unroll
                for (int cc = 0; cc < 16; ++cc) {
                    float r = fmaxf(fmaf(vA[cc], sA[cc], Pv0), 0.f);
                    accA += (g + cc < mA) ? r : 0.f;
                }
            }
            if (g < mB) {
                #pragma unroll
                for (int cc = 0; cc < 16; ++cc) {
                    float r = fmaxf(fmaf(vB[cc], sB[cc], Pv1), 0.f);
                    accB += (g + cc < mB) ? r : 0.f;
                }
            }
        }
        eA += mA;
        eB += mB;
    }
    hm16[(size_t)n0 * 64 + lane]       = (_Float16)((dgA > 0) ? accA / (float)dgA : 0.f);
    hm16[(size_t)(n0 + 1) * 64 + lane] = (_Float16)((dgB > 0) ? accB / (float)dgB : 0.f);
}

// out = relu(x@aw1t + hm@wcomb + ab1 + [deg>0]*bcomb) @ aw2 + ab2   (MFMA)
__global__ void __launch_bounds__(256) k_c2(const float* __restrict__ x,
                                            const _Float16* __restrict__ hm16,
                                            const _Float16* __restrict__ pk,
                                            const float* __restrict__ ab1,
                                            const float* __restrict__ bcomb,
                                            const float* __restrict__ ab2,
                                            const int* __restrict__ off,
                                            float* __restrict__ out) {
    __shared__ _Float16 lsh[4][2][16][64];
    int w = threadIdx.x >> 6, l = threadIdx.x & 63;
    int m0 = blockIdx.x * 128 + w * 32;
    int col = l & 15;

    f32x4 z = {0.f, 0.f, 0.f, 0.f};
    f32x4 acc[2][4];
    #pragma unroll
    for (int s = 0; s < 2; ++s)
        #pragma unroll
        for (int nt = 0; nt < 4; ++nt) acc[s][nt] = z;

    {
        half8 a[2][2];
        #pragma unroll
        for (int s = 0; s < 2; ++s)
            #pragma unroll
            for (int kg = 0; kg < 2; ++kg) {
                int row = m0 + s * 16 + (l & 15);
                if (row >= N_NODES) row = N_NODES - 1;
                a[s][kg] = afrag_f32(x, row, kg, l);
            }
        const _Float16* pk1 = pk + 2 * 4096;
        #pragma unroll
        for (int nt = 0; nt < 4; ++nt)
            #pragma unroll
            for (int kg = 0; kg < 2; ++kg) {
                half8 b = *(const half8*)(pk1 + ((nt * 2 + kg) * 64 + l) * 8);
                acc[0][nt] = __builtin_amdgcn_mfma_f32_16x16x32_f16(a[0][kg], b, acc[0][nt], 0, 0, 0);
                acc[1][nt] = __builtin_amdgcn_mfma_f32_16x16x32_f16(a[1][kg], b, acc[1][nt], 0, 0, 0);
            }
    }
    {
        half8 a[2][2];
        #pragma unroll
        for (int s = 0; s < 2; ++s)
            #pragma unroll
            for (int kg = 0; kg < 2; ++kg) {
                int row = m0 + s * 16 + (l & 15);
                if (row >= N_NODES) row = N_NODES - 1;
                a[s][kg] = *(const half8*)(hm16 + (size_t)row * 64 + kg * 32 + ((l >> 4) << 3));
            }
        const _Float16* pk2 = pk + 3 * 4096;
        #pragma unroll
        for (int nt = 0; nt < 4; ++nt)
            #pragma unroll
            for (int kg = 0; kg < 2; ++kg) {
                half8 b = *(const half8*)(pk2 + ((nt * 2 + kg) * 64 + l) * 8);
                acc[0][nt] = __builtin_amdgcn_mfma_f32_16x16x32_f16(a[0][kg], b, acc[0][nt], 0, 0, 0);
                acc[1][nt] = __builtin_amdgcn_mfma_f32_16x16x32_f16(a[1][kg], b, acc[1][nt], 0, 0, 0);
            }
    }

    float a1n[4], bcn[4];
    #pragma unroll
    for (int nt = 0; nt < 4; ++nt) {
        int n = nt * 16 + col;
        a1n[nt] = ab1[n];
        bcn[nt] = bcomb[n];
    }
    #pragma unroll
    for (int s = 0; s < 2; ++s)
        #pragma unroll
        for (int r = 0; r < 4; ++r) {
            int row = ((l >> 4) << 2) + r;
            int m = m0 + s * 16 + row;
            int dg = (m < N_NODES) ? (off[m + 1] - off[m]) : 0;
            #pragma unroll
            for (int nt = 0; nt < 4; ++nt) {
                int n = nt * 16 + col;
                float v = acc[s][nt][r] + a1n[nt] + ((dg > 0) ? bcn[nt] : 0.f);
                v = fmaxf(v, 0.f);
                lsh[w][s][row][n ^ ((row & 7) << 3)] = (_Float16)v;
            }
        }
    __syncthreads();

    f32x4 acc2[2][4];
    #pragma unroll
    for (int s = 0; s < 2; ++s)
        #pragma unroll
        for (int nt = 0; nt < 4; ++nt) acc2[s][nt] = z;
    {
        half8 a[2][2];
        #pragma unroll
        for (int s = 0; s < 2; ++s)
            #pragma unroll
            for (int kg = 0; kg < 2; ++kg) {
                int rr = l & 15;
                int c0 = (kg * 32 + ((l >> 4) << 3)) ^ ((rr & 7) << 3);
                a[s][kg] = *(const half8*)&lsh[w][s][rr][c0];
            }
        const _Float16* pk3 = pk + 4 * 4096;
        #pragma unroll
        for (int nt = 0; nt < 4; ++nt)
            #pragma unroll
            for (int kg = 0; kg < 2; ++kg) {
                half8 b = *(const half8*)(pk3 + ((nt * 2 + kg) * 64 + l) * 8);
                acc2[0][nt] = __builtin_amdgcn_mfma_f32_16x16x32_f16(a[0][kg], b, acc2[0][nt], 0, 0, 0);
                acc2[1][nt] = __builtin_amdgcn_mfma_f32_16x16x32_f16(a[1][kg], b, acc2[1][nt], 0, 0, 0);
            }
    }

    float a2n[4];
    #pragma unroll
    for (int nt = 0; nt < 4; ++nt) a2n[nt] = ab2[nt * 16 + col];
    #pragma unroll
    for (int s = 0; s < 2; ++s)
        #pragma unroll
        for (int r = 0; r < 4; ++r) {
            int m = m0 + s * 16 + ((l >> 4) << 2) + r;
            if (m >= N_NODES) continue;
            #pragma unroll
            for (int nt = 0; nt < 4; ++nt)
                out[(size_t)m * 64 + nt * 16 + col] = acc2[s][nt][r] + a2n[nt];
        }
}

extern "C" void kernel_launch(void* const* d_in, const int* in_sizes, int n_in,
                              void* d_out, int out_size, void* d_ws, size_t ws_size,
                              hipStream_t stream) {
    const float* x   = (const float*)d_in[0];
    const int*   ei  = (const int*)d_in[1];
    const int*   ej  = ((const int*)d_in[1]) + N_EDGES;
    const float* pos = (const float*)d_in[2];
    const float* mw1 = (const float*)d_in[3];
    const float* mb1 = (const float*)d_in[4];
    const float* mw2 = (const float*)d_in[5];
    const float* mb2 = (const float*)d_in[6];
    const float* aw1 = (const float*)d_in[7];
    const float* ab1 = (const float*)d_in[8];
    const float* aw2 = (const float*)d_in[9];
    const float* ab2 = (const float*)d_in[10];

    char* ws = (char*)d_ws;
    int*         off    = (int*)(ws + WS_OFF);
    int*         pcur   = (int*)(ws + WS_PCUR);
    int*         B      = (int*)(ws + WS_B);
    int*         sj     = (int*)(ws + WS_SJ);
    float*       wcomb  = (float*)(ws + WS_WCOMB);
    float*       bcomb  = (float*)(ws + WS_BCOMB);
    _Float16*    pk     = (_Float16*)(ws + WS_PK);
    signed char* Qi8    = (signed char*)(ws + WS_QI8);
    float*       Qs     = (float*)(ws + WS_QS);
    int*         binned = (int*)(ws + WS_BIN);
    _Float16*    hm16   = (_Float16*)(ws + WS_HM16);
    float*       out    = (float*)d_out;

    const int NBT = (N_NODES + 127) / 128;        // 782
    const int NBB = (N_EDGES + EB - 1) / EB;      // 196
    hipLaunchKernelGGL(k_init0, dim3(1), dim3(128), 0, stream, pcur);
    hipLaunchKernelGGL(k_binc,  dim3(NBB), dim3(256), 0, stream, ei, ej, pcur, binned);
    hipLaunchKernelGGL(k_scanB, dim3(1), dim3(128), 0, stream, pcur, B);
    hipLaunchKernelGGL(k_fill3, dim3(NPART), dim3(256), 0, stream, binned, B, off, sj);
    hipLaunchKernelGGL(k_wcomb, dim3(17), dim3(256), 0, stream, mw2, mb2, aw1, wcomb, bcomb);
    hipLaunchKernelGGL(k_wpack, dim3(5), dim3(256), 0, stream, mw1, aw1, wcomb, aw2, pk);
    hipLaunchKernelGGL(k_pre,   dim3(NBT), dim3(256), 0, stream, x, pos, mw1, mb1, pk, out, Qi8, Qs);
    hipLaunchKernelGGL(k_c1,    dim3(N_NODES / 8), dim3(256), 0, stream,
                       Qi8, Qs, off, sj, out, hm16);
    hipLaunchKernelGGL(k_c2,    dim3(NBT), dim3(256), 0, stream,
                       x, hm16, pk, ab1, bcomb, ab2, off, out);
}

// Round 14
// 168.075 us; speedup vs baseline: 1.1355x; 1.0486x over previous
//
#include <hip/hip_runtime.h>
#include <hip/hip_fp16.h>

#define N_NODES 100000
#define N_EDGES 1600000
#define NPART 98           // partitions of 1024 nodes
#define CAP   20480        // bucket capacity
#define EB    8192         // edges per k_binc block

typedef _Float16 half8 __attribute__((ext_vector_type(8)));
typedef float f32x4 __attribute__((ext_vector_type(4)));

// ---------------- workspace layout (bytes) ----------------
#define WS_OFF   0          // int[N+1]
#define WS_PCUR  400016     // int[128]
#define WS_B     400528     // int[128]
#define WS_SJ    401040     // int[E]           (6.4 MB)
#define WS_WCOMB 6801040    // float[64*64]
#define WS_BCOMB 6817424    // float[64]
#define WS_PK    6817680    // _Float16[5*4096] (40 KB) B-frag packed weights
#define WS_QI8   6858640    // int8[N*64]       (6.4 MB)
#define WS_QS    13258640   // float[N]         (400 KB)
#define WS_BIN   19658640   // int[NPART*CAP] (8MB) OVERLAPS hm16 - disjoint lifetimes
#define WS_HM16  19658640   // _Float16[N*64]

__global__ void k_init0(int* pcur) {
    int t = threadIdx.x;
    if (t < NPART) pcur[t] = t * CAP;
}

// 3-phase bin: count -> reserve -> re-read (L2-hot) + scatter.
__global__ void __launch_bounds__(256) k_binc(const int* __restrict__ ei,
                                              const int* __restrict__ ej,
                                              int* pcur, int* __restrict__ binned) {
    __shared__ int cnt[NPART];
    __shared__ int wcur[NPART];
    int t = threadIdx.x;
    for (int q = t; q < NPART; q += 256) cnt[q] = 0;
    __syncthreads();
    int base_e = blockIdx.x * EB;
    #pragma unroll 2
    for (int it = 0; it < EB / 1024; ++it) {
        int e = base_e + it * 1024 + t * 4;
        if (e < N_EDGES) {
            int4 iv = *(const int4*)(ei + e);
            atomicAdd(&cnt[iv.x >> 10], 1);
            atomicAdd(&cnt[iv.y >> 10], 1);
            atomicAdd(&cnt[iv.z >> 10], 1);
            atomicAdd(&cnt[iv.w >> 10], 1);
        }
    }
    __syncthreads();
    for (int q = t; q < NPART; q += 256)
        wcur[q] = cnt[q] ? atomicAdd(&pcur[q], cnt[q]) : 0;
    __syncthreads();
    #pragma unroll 2
    for (int it = 0; it < EB / 1024; ++it) {
        int e = base_e + it * 1024 + t * 4;
        if (e < N_EDGES) {
            int4 iv = *(const int4*)(ei + e);
            int4 jv = *(const int4*)(ej + e);
            int a, p;
            p = iv.x >> 10; a = atomicAdd(&wcur[p], 1);
            if (a < (p + 1) * CAP) binned[a] = ((iv.x & 1023) << 17) | jv.x;
            p = iv.y >> 10; a = atomicAdd(&wcur[p], 1);
            if (a < (p + 1) * CAP) binned[a] = ((iv.y & 1023) << 17) | jv.y;
            p = iv.z >> 10; a = atomicAdd(&wcur[p], 1);
            if (a < (p + 1) * CAP) binned[a] = ((iv.z & 1023) << 17) | jv.z;
            p = iv.w >> 10; a = atomicAdd(&wcur[p], 1);
            if (a < (p + 1) * CAP) binned[a] = ((iv.w & 1023) << 17) | jv.w;
        }
    }
}

__global__ void k_scanB(const int* __restrict__ pcur, int* B) {
    __shared__ int s[128];
    int t = threadIdx.x;
    int c = 0;
    if (t < NPART) c = min(pcur[t] - t * CAP, CAP);
    s[t] = c;
    __syncthreads();
    for (int o = 1; o < 128; o <<= 1) {
        int a = (t >= o) ? s[t - o] : 0;
        __syncthreads();
        s[t] += a;
        __syncthreads();
    }
    if (t < NPART) B[t] = s[t] - c;
    if (t == NPART - 1) B[NPART] = s[t];
}

// per-partition counting sort: LDS histogram -> off[] + sj scatter. No global atomics.
__global__ void __launch_bounds__(256) k_fill3(const int* __restrict__ binned,
                                               const int* __restrict__ B,
                                               int* __restrict__ off,
                                               int* __restrict__ sj) {
    __shared__ int hist[1024];
    __shared__ int tsum[256];
    int p = blockIdx.x, t = threadIdx.x;
    int b0g = B[p];
    int cnt_p = B[p + 1] - b0g;
    const int* src = binned + p * CAP;

    #pragma unroll
    for (int q = 0; q < 4; ++q) hist[t * 4 + q] = 0;
    __syncthreads();
    for (int e = t; e < cnt_p; e += 256) atomicAdd(&hist[src[e] >> 17], 1);
    __syncthreads();

    int b0 = hist[t * 4], b1 = hist[t * 4 + 1], b2 = hist[t * 4 + 2], b3 = hist[t * 4 + 3];
    int c1 = b0, c2 = c1 + b1, c3 = c2 + b2, tot = c3 + b3;
    tsum[t] = tot;
    __syncthreads();
    for (int o = 1; o < 256; o <<= 1) {
        int a = (t >= o) ? tsum[t - o] : 0;
        __syncthreads();
        tsum[t] += a;
        __syncthreads();
    }
    int tex = tsum[t] - tot;
    hist[t * 4]     = tex;
    hist[t * 4 + 1] = tex + c1;
    hist[t * 4 + 2] = tex + c2;
    hist[t * 4 + 3] = tex + c3;
    __syncthreads();

    int lo = p * 1024;
    #pragma unroll
    for (int q = 0; q < 4; ++q) {
        int n = t * 4 + q, g = lo + n;
        if (g < N_NODES) off[g] = b0g + hist[n];
    }
    if (p == NPART - 1 && t == 0) off[N_NODES] = B[NPART];
    __syncthreads();

    for (int e = t; e < cnt_p; e += 256) {
        int v = src[e];
        int slot = atomicAdd(&hist[v >> 17], 1);
        sj[b0g + slot] = v & 0x1FFFF;
    }
}

__global__ void k_wcomb(const float* __restrict__ mw2, const float* __restrict__ mb2,
                        const float* __restrict__ aw1, float* wcomb, float* bcomb) {
    int o = blockIdx.x * blockDim.x + threadIdx.x;
    if (o < 64 * 64) {
        int c = o >> 6, k = o & 63;
        float s = 0.f;
        #pragma unroll 8
        for (int a = 0; a < 64; ++a) s += mw2[c * 64 + a] * aw1[(64 + a) * 64 + k];
        wcomb[o] = s;
    } else if (o < 64 * 64 + 64) {
        int k = o - 64 * 64;
        float s = 0.f;
        #pragma unroll 8
        for (int a = 0; a < 64; ++a) s += mb2[a] * aw1[(64 + a) * 64 + k];
        bcomb[k] = s;
    }
}

// Pack 5 weight matrices into MFMA B-fragment order.
__global__ void k_wpack(const float* __restrict__ mw1, const float* __restrict__ aw1,
                        const float* __restrict__ wcomb, const float* __restrict__ aw2,
                        _Float16* __restrict__ pk) {
    int mat = blockIdx.x;
    const float* src = (mat == 0) ? mw1 : (mat == 1) ? (mw1 + 4096)
                     : (mat == 2) ? aw1 : (mat == 3) ? wcomb : aw2;
    _Float16* dst = pk + mat * 4096;
    for (int t = threadIdx.x; t < 4096; t += 256) {
        int b_ = t & 7, l = (t >> 3) & 63, z = t >> 9;
        int kg = z & 1, nt = z >> 1;
        int k = kg * 32 + ((l >> 4) << 3) + b_;
        int n = nt * 16 + (l & 15);
        dst[t] = (_Float16)src[k * 64 + n];
    }
}

// ---- MFMA helpers ----
__device__ __forceinline__ half8 afrag_f32(const float* src, int row, int kg, int l) {
    const float* p = src + (size_t)row * 64 + kg * 32 + ((l >> 4) << 3);
    float4 u = *(const float4*)p;
    float4 v = *(const float4*)(p + 4);
    half8 h;
    h[0] = (_Float16)u.x; h[1] = (_Float16)u.y; h[2] = (_Float16)u.z; h[3] = (_Float16)u.w;
    h[4] = (_Float16)v.x; h[5] = (_Float16)v.y; h[6] = (_Float16)v.z; h[7] = (_Float16)v.w;
    return h;
}

// Fused: P' = x@W1a + mb1 - pos@W1p (fp32 -> d_out temp)
//        Q' = x@W1b       + pos@W1p -> int8 row-quantized + fp32 scale
__global__ void __launch_bounds__(256) k_pre(const float* __restrict__ x,
                                             const float* __restrict__ pos,
                                             const float* __restrict__ mw1,
                                             const float* __restrict__ mb1,
                                             const _Float16* __restrict__ pk,
                                             float* __restrict__ P,
                                             signed char* __restrict__ Qi8,
                                             float* __restrict__ Qs) {
    int w = threadIdx.x >> 6, l = threadIdx.x & 63;
    int m0 = blockIdx.x * 128 + w * 32;

    half8 a[2][2];
    #pragma unroll
    for (int s = 0; s < 2; ++s)
        #pragma unroll
        for (int kg = 0; kg < 2; ++kg) {
            int row = m0 + s * 16 + (l & 15);
            if (row >= N_NODES) row = N_NODES - 1;
            a[s][kg] = afrag_f32(x, row, kg, l);
        }

    f32x4 z = {0.f, 0.f, 0.f, 0.f};
    f32x4 accP[2][4], accQ[2][4];
    #pragma unroll
    for (int s = 0; s < 2; ++s)
        #pragma unroll
        for (int nt = 0; nt < 4; ++nt) { accP[s][nt] = z; accQ[s][nt] = z; }

    #pragma unroll
    for (int nt = 0; nt < 4; ++nt)
        #pragma unroll
        for (int kg = 0; kg < 2; ++kg) {
            half8 b = *(const half8*)(pk + ((nt * 2 + kg) * 64 + l) * 8);
            accP[0][nt] = __builtin_amdgcn_mfma_f32_16x16x32_f16(a[0][kg], b, accP[0][nt], 0, 0, 0);
            accP[1][nt] = __builtin_amdgcn_mfma_f32_16x16x32_f16(a[1][kg], b, accP[1][nt], 0, 0, 0);
        }
    const _Float16* pkb = pk + 4096;
    #pragma unroll
    for (int nt = 0; nt < 4; ++nt)
        #pragma unroll
        for (int kg = 0; kg < 2; ++kg) {
            half8 b = *(const half8*)(pkb + ((nt * 2 + kg) * 64 + l) * 8);
            accQ[0][nt] = __builtin_amdgcn_mfma_f32_16x16x32_f16(a[0][kg], b, accQ[0][nt], 0, 0, 0);
            accQ[1][nt] = __builtin_amdgcn_mfma_f32_16x16x32_f16(a[1][kg], b, accQ[1][nt], 0, 0, 0);
        }

    int col = l & 15;
    float wx[4], wy[4], wz[4], bb[4];
    #pragma unroll
    for (int nt = 0; nt < 4; ++nt) {
        int n = nt * 16 + col;
        wx[nt] = mw1[128 * 64 + n];
        wy[nt] = mw1[129 * 64 + n];
        wz[nt] = mw1[130 * 64 + n];
        bb[nt] = mb1[n];
    }
    #pragma unroll
    for (int s = 0; s < 2; ++s)
        #pragma unroll
        for (int r = 0; r < 4; ++r) {
            int m = m0 + s * 16 + ((l >> 4) << 2) + r;
            if (m >= N_NODES) continue;   // uniform across the 16-lane group
            float px = pos[3 * m], py = pos[3 * m + 1], pz = pos[3 * m + 2];
            float qn[4];
            #pragma unroll
            for (int nt = 0; nt < 4; ++nt) {
                int n = nt * 16 + col;
                float pd = px * wx[nt] + py * wy[nt] + pz * wz[nt];
                P[(size_t)m * 64 + n] = accP[s][nt][r] + bb[nt] - pd;
                qn[nt] = accQ[s][nt][r] + pd;
            }
            float mx = fmaxf(fmaxf(fabsf(qn[0]), fabsf(qn[1])),
                             fmaxf(fabsf(qn[2]), fabsf(qn[3])));
            #pragma unroll
            for (int d = 1; d < 16; d <<= 1) mx = fmaxf(mx, __shfl_xor(mx, d, 64));
            float inv = (mx > 0.f) ? 127.f / mx : 0.f;
            #pragma unroll
            for (int nt = 0; nt < 4; ++nt)
                Qi8[(size_t)m * 64 + nt * 16 + col] = (signed char)(int)rintf(qn[nt] * inv);
            if (col == 0) Qs[m] = mx * (1.f / 127.f);
        }
}

// ---- k_c1: named-register 16-deep gather groups ----
// G1: issue gather for edge G+k (j from constant-index readlane -> SGPR,
//     byte-gather + scalar scale load). All 16 issue before any consume.
// G2: consume with per-element wave-uniform-free mask.
#define G1(k) int j##k = __builtin_amdgcn_readlane(jv, G + k); \
              float b##k = (float)Qi8[(size_t)j##k * 64 + lane]; \
              float s##k = Qs[j##k];
#define G2(k) r += (G + k < m) ? fmaxf(fmaf(b##k, s##k, Pv), 0.f) : 0.f;

template<int G>
__device__ __forceinline__ float grp16(int jv, int m, float Pv, int lane,
                                       const signed char* __restrict__ Qi8,
                                       const float* __restrict__ Qs) {
    if (G >= m) return 0.f;
    G1(0)  G1(1)  G1(2)  G1(3)  G1(4)  G1(5)  G1(6)  G1(7)
    G1(8)  G1(9)  G1(10) G1(11) G1(12) G1(13) G1(14) G1(15)
    float r = 0.f;
    G2(0)  G2(1)  G2(2)  G2(3)  G2(4)  G2(5)  G2(6)  G2(7)
    G2(8)  G2(9)  G2(10) G2(11) G2(12) G2(13) G2(14) G2(15)
    return r;
}

// Edge aggregation: hmean = mean(relu(P'_i + Qi8[j]*Qs[j])) -> fp16.
// One node per wave; 16 gathers in flight from NAMED registers (no scratch);
// nontemporal on streaming P/sj/hm16 so Qi8 keeps the L2.
__global__ void __launch_bounds__(256) k_c1(const signed char* __restrict__ Qi8,
                                            const float* __restrict__ Qs,
                                            const int* __restrict__ off,
                                            const int* __restrict__ sj,
                                            const float* __restrict__ Phm,
                                            _Float16* __restrict__ hm16) {
    int wave = threadIdx.x >> 6, lane = threadIdx.x & 63;
    int node = blockIdx.x * 4 + wave;
    if (node >= N_NODES) return;
    float Pv = __builtin_nontemporal_load(&Phm[(size_t)node * 64 + lane]);
    int o0 = off[node], o1 = off[node + 1];
    int dg = o1 - o0;
    float acc = 0.f;
    for (int base = o0; base < o1; base += 64) {
        int m = min(64, o1 - base);
        int jv = (lane < m) ? __builtin_nontemporal_load(&sj[base + lane]) : 0;
        acc += grp16<0>(jv, m, Pv, lane, Qi8, Qs);
        acc += grp16<16>(jv, m, Pv, lane, Qi8, Qs);
        acc += grp16<32>(jv, m, Pv, lane, Qi8, Qs);
        acc += grp16<48>(jv, m, Pv, lane, Qi8, Qs);
    }
    _Float16 hv = (_Float16)((dg > 0) ? acc / (float)dg : 0.f);
    __builtin_nontemporal_store(hv, &hm16[(size_t)node * 64 + lane]);
}

// out = relu(x@aw1t + hm@wcomb + ab1 + [deg>0]*bcomb) @ aw2 + ab2   (MFMA)
__global__ void __launch_bounds__(256) k_c2(const float* __restrict__ x,
                                            const _Float16* __restrict__ hm16,
                                            const _Float16* __restrict__ pk,
                                            const float* __restrict__ ab1,
                                            const float* __restrict__ bcomb,
                                            const float* __restrict__ ab2,
                                            const int* __restrict__ off,
                                            float* __restrict__ out) {
    __shared__ _Float16 lsh[4][2][16][64];
    int w = threadIdx.x >> 6, l = threadIdx.x & 63;
    int m0 = blockIdx.x * 128 + w * 32;
    int col = l & 15;

    f32x4 z = {0.f, 0.f, 0.f, 0.f};
    f32x4 acc[2][4];
    #pragma unroll
    for (int s = 0; s < 2; ++s)
        #pragma unroll
        for (int nt = 0; nt < 4; ++nt) acc[s][nt] = z;

    {
        half8 a[2][2];
        #pragma unroll
        for (int s = 0; s < 2; ++s)
            #pragma unroll
            for (int kg = 0; kg < 2; ++kg) {
                int row = m0 + s * 16 + (l & 15);
                if (row >= N_NODES) row = N_NODES - 1;
                a[s][kg] = afrag_f32(x, row, kg, l);
            }
        const _Float16* pk1 = pk + 2 * 4096;
        #pragma unroll
        for (int nt = 0; nt < 4; ++nt)
            #pragma unroll
            for (int kg = 0; kg < 2; ++kg) {
                half8 b = *(const half8*)(pk1 + ((nt * 2 + kg) * 64 + l) * 8);
                acc[0][nt] = __builtin_amdgcn_mfma_f32_16x16x32_f16(a[0][kg], b, acc[0][nt], 0, 0, 0);
                acc[1][nt] = __builtin_amdgcn_mfma_f32_16x16x32_f16(a[1][kg], b, acc[1][nt], 0, 0, 0);
            }
    }
    {
        half8 a[2][2];
        #pragma unroll
        for (int s = 0; s < 2; ++s)
            #pragma unroll
            for (int kg = 0; kg < 2; ++kg) {
                int row = m0 + s * 16 + (l & 15);
                if (row >= N_NODES) row = N_NODES - 1;
                a[s][kg] = *(const half8*)(hm16 + (size_t)row * 64 + kg * 32 + ((l >> 4) << 3));
            }
        const _Float16* pk2 = pk + 3 * 4096;
        #pragma unroll
        for (int nt = 0; nt < 4; ++nt)
            #pragma unroll
            for (int kg = 0; kg < 2; ++kg) {
                half8 b = *(const half8*)(pk2 + ((nt * 2 + kg) * 64 + l) * 8);
                acc[0][nt] = __builtin_amdgcn_mfma_f32_16x16x32_f16(a[0][kg], b, acc[0][nt], 0, 0, 0);
                acc[1][nt] = __builtin_amdgcn_mfma_f32_16x16x32_f16(a[1][kg], b, acc[1][nt], 0, 0, 0);
            }
    }

    float a1n[4], bcn[4];
    #pragma unroll
    for (int nt = 0; nt < 4; ++nt) {
        int n = nt * 16 + col;
        a1n[nt] = ab1[n];
        bcn[nt] = bcomb[n];
    }
    #pragma unroll
    for (int s = 0; s < 2; ++s)
        #pragma unroll
        for (int r = 0; r < 4; ++r) {
            int row = ((l >> 4) << 2) + r;
            int m = m0 + s * 16 + row;
            int dg = (m < N_NODES) ? (off[m + 1] - off[m]) : 0;
            #pragma unroll
            for (int nt = 0; nt < 4; ++nt) {
                int n = nt * 16 + col;
                float v = acc[s][nt][r] + a1n[nt] + ((dg > 0) ? bcn[nt] : 0.f);
                v = fmaxf(v, 0.f);
                lsh[w][s][row][n ^ ((row & 7) << 3)] = (_Float16)v;
            }
        }
    __syncthreads();

    f32x4 acc2[2][4];
    #pragma unroll
    for (int s = 0; s < 2; ++s)
        #pragma unroll
        for (int nt = 0; nt < 4; ++nt) acc2[s][nt] = z;
    {
        half8 a[2][2];
        #pragma unroll
        for (int s = 0; s < 2; ++s)
            #pragma unroll
            for (int kg = 0; kg < 2; ++kg) {
                int rr = l & 15;
                int c0 = (kg * 32 + ((l >> 4) << 3)) ^ ((rr & 7) << 3);
                a[s][kg] = *(const half8*)&lsh[w][s][rr][c0];
            }
        const _Float16* pk3 = pk + 4 * 4096;
        #pragma unroll
        for (int nt = 0; nt < 4; ++nt)
            #pragma unroll
            for (int kg = 0; kg < 2; ++kg) {
                half8 b = *(const half8*)(pk3 + ((nt * 2 + kg) * 64 + l) * 8);
                acc2[0][nt] = __builtin_amdgcn_mfma_f32_16x16x32_f16(a[0][kg], b, acc2[0][nt], 0, 0, 0);
                acc2[1][nt] = __builtin_amdgcn_mfma_f32_16x16x32_f16(a[1][kg], b, acc2[1][nt], 0, 0, 0);
            }
    }

    float a2n[4];
    #pragma unroll
    for (int nt = 0; nt < 4; ++nt) a2n[nt] = ab2[nt * 16 + col];
    #pragma unroll
    for (int s = 0; s < 2; ++s)
        #pragma unroll
        for (int r = 0; r < 4; ++r) {
            int m = m0 + s * 16 + ((l >> 4) << 2) + r;
            if (m >= N_NODES) continue;
            #pragma unroll
            for (int nt = 0; nt < 4; ++nt)
                out[(size_t)m * 64 + nt * 16 + col] = acc2[s][nt][r] + a2n[nt];
        }
}

extern "C" void kernel_launch(void* const* d_in, const int* in_sizes, int n_in,
                              void* d_out, int out_size, void* d_ws, size_t ws_size,
                              hipStream_t stream) {
    const float* x   = (const float*)d_in[0];
    const int*   ei  = (const int*)d_in[1];
    const int*   ej  = ((const int*)d_in[1]) + N_EDGES;
    const float* pos = (const float*)d_in[2];
    const float* mw1 = (const float*)d_in[3];
    const float* mb1 = (const float*)d_in[4];
    const float* mw2 = (const float*)d_in[5];
    const float* mb2 = (const float*)d_in[6];
    const float* aw1 = (const float*)d_in[7];
    const float* ab1 = (const float*)d_in[8];
    const float* aw2 = (const float*)d_in[9];
    const float* ab2 = (const float*)d_in[10];

    char* ws = (char*)d_ws;
    int*         off    = (int*)(ws + WS_OFF);
    int*         pcur   = (int*)(ws + WS_PCUR);
    int*         B      = (int*)(ws + WS_B);
    int*         sj     = (int*)(ws + WS_SJ);
    float*       wcomb  = (float*)(ws + WS_WCOMB);
    float*       bcomb  = (float*)(ws + WS_BCOMB);
    _Float16*    pk     = (_Float16*)(ws + WS_PK);
    signed char* Qi8    = (signed char*)(ws + WS_QI8);
    float*       Qs     = (float*)(ws + WS_QS);
    int*         binned = (int*)(ws + WS_BIN);
    _Float16*    hm16   = (_Float16*)(ws + WS_HM16);
    float*       out    = (float*)d_out;

    const int NBT = (N_NODES + 127) / 128;        // 782
    const int NBB = (N_EDGES + EB - 1) / EB;      // 196
    hipLaunchKernelGGL(k_init0, dim3(1), dim3(128), 0, stream, pcur);
    hipLaunchKernelGGL(k_binc,  dim3(NBB), dim3(256), 0, stream, ei, ej, pcur, binned);
    hipLaunchKernelGGL(k_scanB, dim3(1), dim3(128), 0, stream, pcur, B);
    hipLaunchKernelGGL(k_fill3, dim3(NPART), dim3(256), 0, stream, binned, B, off, sj);
    hipLaunchKernelGGL(k_wcomb, dim3(17), dim3(256), 0, stream, mw2, mb2, aw1, wcomb, bcomb);
    hipLaunchKernelGGL(k_wpack, dim3(5), dim3(256), 0, stream, mw1, aw1, wcomb, aw2, pk);
    hipLaunchKernelGGL(k_pre,   dim3(NBT), dim3(256), 0, stream, x, pos, mw1, mb1, pk, out, Qi8, Qs);
    hipLaunchKernelGGL(k_c1,    dim3((N_NODES + 3) / 4), dim3(256), 0, stream,
                       Qi8, Qs, off, sj, out, hm16);
    hipLaunchKernelGGL(k_c2,    dim3(NBT), dim3(256), 0, stream,
                       x, hm16, pk, ab1, bcomb, ab2, off, out);
}

// Round 15
// 162.389 us; speedup vs baseline: 1.1752x; 1.0350x over previous
//
#include <hip/hip_runtime.h>
#include <hip/hip_fp16.h>

#define N_NODES 100000
#define N_EDGES 1600000
#define NPART 98           // partitions of 1024 nodes
#define CAP   20480        // bucket capacity
#define EB    8192         // edges per binc block
#define NBB   ((N_EDGES + EB - 1) / EB)        // 196
#define NBT   ((N_NODES + 127) / 128)          // 782

typedef _Float16 half8 __attribute__((ext_vector_type(8)));
typedef float f32x4 __attribute__((ext_vector_type(4)));

// ---------------- workspace layout (bytes) ----------------
#define WS_OFF   0          // int[N+1]
#define WS_PCUR  400016     // int[128]
#define WS_B     400528     // int[128]
#define WS_SJ    401040     // int[E]           (6.4 MB)
#define WS_BCOMB 6817424    // float[64]
#define WS_PK    6817680    // _Float16[5*4096] (40 KB)
#define WS_Q     6858640    // _Float16[N*64]   (12.8 MB) ends 19658640
#define WS_BIN   19658640   // int[NPART*CAP] (8MB) OVERLAPS hm16 - disjoint lifetimes
#define WS_HM16  19658640   // _Float16[N*64]

// ---- K1: weight packing (wcomb inline) + bcomb + pcur init ----
__global__ void __launch_bounds__(256) k_setup(const float* __restrict__ mw1,
                                               const float* __restrict__ mw2,
                                               const float* __restrict__ mb2,
                                               const float* __restrict__ aw1,
                                               const float* __restrict__ aw2,
                                               _Float16* __restrict__ pk,
                                               float* __restrict__ bcomb,
                                               int* __restrict__ pcur) {
    __shared__ float wc[4096];
    int blk = blockIdx.x, t = threadIdx.x;
    if (blk < 5) {
        const float* src;
        if (blk == 3) {
            for (int o = t; o < 4096; o += 256) {
                int c = o >> 6, k = o & 63;
                float s = 0.f;
                #pragma unroll 8
                for (int a = 0; a < 64; ++a) s += mw2[c * 64 + a] * aw1[(64 + a) * 64 + k];
                wc[o] = s;
            }
            __syncthreads();
            src = wc;
        } else {
            src = (blk == 0) ? mw1 : (blk == 1) ? (mw1 + 4096)
                : (blk == 2) ? aw1 : aw2;
        }
        _Float16* dst = pk + blk * 4096;
        for (int o = t; o < 4096; o += 256) {
            int b_ = o & 7, l = (o >> 3) & 63, z = o >> 9;
            int kg = z & 1, nt = z >> 1;
            int k = kg * 32 + ((l >> 4) << 3) + b_;
            int n = nt * 16 + (l & 15);
            dst[o] = (_Float16)src[k * 64 + n];
        }
    } else {
        if (t < 64) {
            float s = 0.f;
            #pragma unroll 8
            for (int a = 0; a < 64; ++a) s += mb2[a] * aw1[(64 + a) * 64 + t];
            bcomb[t] = s;
        }
        if (t < 128) pcur[t] = t * CAP;
    }
}

// ---- MFMA helpers ----
__device__ __forceinline__ half8 afrag_f32(const float* src, int row, int kg, int l) {
    const float* p = src + (size_t)row * 64 + kg * 32 + ((l >> 4) << 3);
    float4 u = *(const float4*)p;
    float4 v = *(const float4*)(p + 4);
    half8 h;
    h[0] = (_Float16)u.x; h[1] = (_Float16)u.y; h[2] = (_Float16)u.z; h[3] = (_Float16)u.w;
    h[4] = (_Float16)v.x; h[5] = (_Float16)v.y; h[6] = (_Float16)v.z; h[7] = (_Float16)v.w;
    return h;
}

// ---- K2: binc (blocks 0..NBB-1)  ||  pre (blocks NBB..NBB+NBT-1) ----
__global__ void __launch_bounds__(256) k_binpre(const int* __restrict__ ei,
                                                const int* __restrict__ ej,
                                                int* pcur, int* __restrict__ binned,
                                                const float* __restrict__ x,
                                                const float* __restrict__ pos,
                                                const float* __restrict__ mw1,
                                                const float* __restrict__ mb1,
                                                const _Float16* __restrict__ pk,
                                                float* __restrict__ P,
                                                _Float16* __restrict__ Q16) {
    __shared__ int cnt[NPART];
    __shared__ int wcur[NPART];
    int t = threadIdx.x;
    if (blockIdx.x < NBB) {
        // ---- 3-phase bin: count -> reserve -> re-read (L2-hot) + scatter ----
        for (int q = t; q < NPART; q += 256) cnt[q] = 0;
        __syncthreads();
        int base_e = blockIdx.x * EB;
        #pragma unroll 2
        for (int it = 0; it < EB / 1024; ++it) {
            int e = base_e + it * 1024 + t * 4;
            if (e < N_EDGES) {
                int4 iv = *(const int4*)(ei + e);
                atomicAdd(&cnt[iv.x >> 10], 1);
                atomicAdd(&cnt[iv.y >> 10], 1);
                atomicAdd(&cnt[iv.z >> 10], 1);
                atomicAdd(&cnt[iv.w >> 10], 1);
            }
        }
        __syncthreads();
        for (int q = t; q < NPART; q += 256)
            wcur[q] = cnt[q] ? atomicAdd(&pcur[q], cnt[q]) : 0;
        __syncthreads();
        #pragma unroll 2
        for (int it = 0; it < EB / 1024; ++it) {
            int e = base_e + it * 1024 + t * 4;
            if (e < N_EDGES) {
                int4 iv = *(const int4*)(ei + e);
                int4 jv = *(const int4*)(ej + e);
                int a, p;
                p = iv.x >> 10; a = atomicAdd(&wcur[p], 1);
                if (a < (p + 1) * CAP) binned[a] = ((iv.x & 1023) << 17) | jv.x;
                p = iv.y >> 10; a = atomicAdd(&wcur[p], 1);
                if (a < (p + 1) * CAP) binned[a] = ((iv.y & 1023) << 17) | jv.y;
                p = iv.z >> 10; a = atomicAdd(&wcur[p], 1);
                if (a < (p + 1) * CAP) binned[a] = ((iv.z & 1023) << 17) | jv.z;
                p = iv.w >> 10; a = atomicAdd(&wcur[p], 1);
                if (a < (p + 1) * CAP) binned[a] = ((iv.w & 1023) << 17) | jv.w;
            }
        }
        return;
    }
    // ---- pre: P' = x@W1a + mb1 - pos@W1p (fp32); Q' = x@W1b + pos@W1p (fp16) ----
    int bid = blockIdx.x - NBB;
    int w = t >> 6, l = t & 63;
    int m0 = bid * 128 + w * 32;

    half8 a[2][2];
    #pragma unroll
    for (int s = 0; s < 2; ++s)
        #pragma unroll
        for (int kg = 0; kg < 2; ++kg) {
            int row = m0 + s * 16 + (l & 15);
            if (row >= N_NODES) row = N_NODES - 1;
            a[s][kg] = afrag_f32(x, row, kg, l);
        }

    f32x4 z = {0.f, 0.f, 0.f, 0.f};
    f32x4 accP[2][4], accQ[2][4];
    #pragma unroll
    for (int s = 0; s < 2; ++s)
        #pragma unroll
        for (int nt = 0; nt < 4; ++nt) { accP[s][nt] = z; accQ[s][nt] = z; }

    #pragma unroll
    for (int nt = 0; nt < 4; ++nt)
        #pragma unroll
        for (int kg = 0; kg < 2; ++kg) {
            half8 b = *(const half8*)(pk + ((nt * 2 + kg) * 64 + l) * 8);
            accP[0][nt] = __builtin_amdgcn_mfma_f32_16x16x32_f16(a[0][kg], b, accP[0][nt], 0, 0, 0);
            accP[1][nt] = __builtin_amdgcn_mfma_f32_16x16x32_f16(a[1][kg], b, accP[1][nt], 0, 0, 0);
        }
    const _Float16* pkb = pk + 4096;
    #pragma unroll
    for (int nt = 0; nt < 4; ++nt)
        #pragma unroll
        for (int kg = 0; kg < 2; ++kg) {
            half8 b = *(const half8*)(pkb + ((nt * 2 + kg) * 64 + l) * 8);
            accQ[0][nt] = __builtin_amdgcn_mfma_f32_16x16x32_f16(a[0][kg], b, accQ[0][nt], 0, 0, 0);
            accQ[1][nt] = __builtin_amdgcn_mfma_f32_16x16x32_f16(a[1][kg], b, accQ[1][nt], 0, 0, 0);
        }

    int col = l & 15;
    float wx[4], wy[4], wz[4], bb[4];
    #pragma unroll
    for (int nt = 0; nt < 4; ++nt) {
        int n = nt * 16 + col;
        wx[nt] = mw1[128 * 64 + n];
        wy[nt] = mw1[129 * 64 + n];
        wz[nt] = mw1[130 * 64 + n];
        bb[nt] = mb1[n];
    }
    #pragma unroll
    for (int s = 0; s < 2; ++s)
        #pragma unroll
        for (int r = 0; r < 4; ++r) {
            int m = m0 + s * 16 + ((l >> 4) << 2) + r;
            if (m >= N_NODES) continue;
            float px = pos[3 * m], py = pos[3 * m + 1], pz = pos[3 * m + 2];
            #pragma unroll
            for (int nt = 0; nt < 4; ++nt) {
                int n = nt * 16 + col;
                float pd = px * wx[nt] + py * wy[nt] + pz * wz[nt];
                P[(size_t)m * 64 + n] = accP[s][nt][r] + bb[nt] - pd;
                Q16[(size_t)m * 64 + n] = (_Float16)(accQ[s][nt][r] + pd);
            }
        }
}

// ---- K3: per-partition counting sort with INLINE 98-wide prefix scan ----
__global__ void __launch_bounds__(256) k_fill3s(const int* __restrict__ binned,
                                                const int* __restrict__ pcur,
                                                int* __restrict__ off,
                                                int* __restrict__ sj) {
    __shared__ int bs[128];
    __shared__ int hist[1024];
    __shared__ int tsum[256];
    int p = blockIdx.x, t = threadIdx.x;

    // inline scanB (all blocks compute the same 98-prefix; redundant but cheap)
    int c = 0;
    if (t < 128) {
        if (t < NPART) c = min(pcur[t] - t * CAP, CAP);
        bs[t] = c;
    }
    __syncthreads();
    for (int o = 1; o < 128; o <<= 1) {
        int a = 0;
        if (t < 128 && t >= o) a = bs[t - o];
        __syncthreads();
        if (t < 128) bs[t] += a;
        __syncthreads();
    }
    int cp = min(pcur[p] - p * CAP, CAP);
    int b0g = bs[p] - cp;          // exclusive prefix at p
    int cnt_p = cp;
    int total = bs[NPART - 1];
    const int* src = binned + p * CAP;

    #pragma unroll
    for (int q = 0; q < 4; ++q) hist[t * 4 + q] = 0;
    __syncthreads();
    for (int e = t; e < cnt_p; e += 256) atomicAdd(&hist[src[e] >> 17], 1);
    __syncthreads();

    int b0 = hist[t * 4], b1 = hist[t * 4 + 1], b2 = hist[t * 4 + 2], b3 = hist[t * 4 + 3];
    int c1 = b0, c2 = c1 + b1, c3 = c2 + b2, tot = c3 + b3;
    tsum[t] = tot;
    __syncthreads();
    for (int o = 1; o < 256; o <<= 1) {
        int a = (t >= o) ? tsum[t - o] : 0;
        __syncthreads();
        tsum[t] += a;
        __syncthreads();
    }
    int tex = tsum[t] - tot;
    hist[t * 4]     = tex;
    hist[t * 4 + 1] = tex + c1;
    hist[t * 4 + 2] = tex + c2;
    hist[t * 4 + 3] = tex + c3;
    __syncthreads();

    int lo = p * 1024;
    #pragma unroll
    for (int q = 0; q < 4; ++q) {
        int n = t * 4 + q, g = lo + n;
        if (g < N_NODES) off[g] = b0g + hist[n];
    }
    if (p == NPART - 1 && t == 0) off[N_NODES] = total;
    __syncthreads();

    for (int e = t; e < cnt_p; e += 256) {
        int v = src[e];
        int slot = atomicAdd(&hist[v >> 17], 1);
        sj[b0g + slot] = v & 0x1FFFF;
    }
}

// ---- K4: edge aggregation, fp16 Q, named-register 16-deep gather groups ----
#define G1(k) int j##k = __builtin_amdgcn_readlane(jv, G + k); \
              float v##k = (float)Q16[(size_t)j##k * 64 + lane];
#define G2(k) r += (G + k < m) ? fmaxf(Pv + v##k, 0.f) : 0.f;

template<int G>
__device__ __forceinline__ float grp16(int jv, int m, float Pv, int lane,
                                       const _Float16* __restrict__ Q16) {
    if (G >= m) return 0.f;
    G1(0)  G1(1)  G1(2)  G1(3)  G1(4)  G1(5)  G1(6)  G1(7)
    G1(8)  G1(9)  G1(10) G1(11) G1(12) G1(13) G1(14) G1(15)
    float r = 0.f;
    G2(0)  G2(1)  G2(2)  G2(3)  G2(4)  G2(5)  G2(6)  G2(7)
    G2(8)  G2(9)  G2(10) G2(11) G2(12) G2(13) G2(14) G2(15)
    return r;
}

__global__ void __launch_bounds__(256) k_c1(const _Float16* __restrict__ Q16,
                                            const int* __restrict__ off,
                                            const int* __restrict__ sj,
                                            const float* __restrict__ Phm,
                                            _Float16* __restrict__ hm16) {
    int wave = threadIdx.x >> 6, lane = threadIdx.x & 63;
    int node = blockIdx.x * 4 + wave;
    if (node >= N_NODES) return;
    float Pv = __builtin_nontemporal_load(&Phm[(size_t)node * 64 + lane]);
    int o0 = off[node], o1 = off[node + 1];
    int dg = o1 - o0;
    float acc = 0.f;
    for (int base = o0; base < o1; base += 64) {
        int m = min(64, o1 - base);
        int jv = (lane < m) ? __builtin_nontemporal_load(&sj[base + lane]) : 0;
        acc += grp16<0>(jv, m, Pv, lane, Q16);
        acc += grp16<16>(jv, m, Pv, lane, Q16);
        acc += grp16<32>(jv, m, Pv, lane, Q16);
        acc += grp16<48>(jv, m, Pv, lane, Q16);
    }
    _Float16 hv = (_Float16)((dg > 0) ? acc / (float)dg : 0.f);
    __builtin_nontemporal_store(hv, &hm16[(size_t)node * 64 + lane]);
}

// ---- K5: out = relu(x@aw1t + hm@wcomb + ab1 + [deg>0]*bcomb) @ aw2 + ab2 ----
__global__ void __launch_bounds__(256) k_c2(const float* __restrict__ x,
                                            const _Float16* __restrict__ hm16,
                                            const _Float16* __restrict__ pk,
                                            const float* __restrict__ ab1,
                                            const float* __restrict__ bcomb,
                                            const float* __restrict__ ab2,
                                            const int* __restrict__ off,
                                            float* __restrict__ out) {
    __shared__ _Float16 lsh[4][2][16][64];
    int w = threadIdx.x >> 6, l = threadIdx.x & 63;
    int m0 = blockIdx.x * 128 + w * 32;
    int col = l & 15;

    f32x4 z = {0.f, 0.f, 0.f, 0.f};
    f32x4 acc[2][4];
    #pragma unroll
    for (int s = 0; s < 2; ++s)
        #pragma unroll
        for (int nt = 0; nt < 4; ++nt) acc[s][nt] = z;

    {
        half8 a[2][2];
        #pragma unroll
        for (int s = 0; s < 2; ++s)
            #pragma unroll
            for (int kg = 0; kg < 2; ++kg) {
                int row = m0 + s * 16 + (l & 15);
                if (row >= N_NODES) row = N_NODES - 1;
                a[s][kg] = afrag_f32(x, row, kg, l);
            }
        const _Float16* pk1 = pk + 2 * 4096;
        #pragma unroll
        for (int nt = 0; nt < 4; ++nt)
            #pragma unroll
            for (int kg = 0; kg < 2; ++kg) {
                half8 b = *(const half8*)(pk1 + ((nt * 2 + kg) * 64 + l) * 8);
                acc[0][nt] = __builtin_amdgcn_mfma_f32_16x16x32_f16(a[0][kg], b, acc[0][nt], 0, 0, 0);
                acc[1][nt] = __builtin_amdgcn_mfma_f32_16x16x32_f16(a[1][kg], b, acc[1][nt], 0, 0, 0);
            }
    }
    {
        half8 a[2][2];
        #pragma unroll
        for (int s = 0; s < 2; ++s)
            #pragma unroll
            for (int kg = 0; kg < 2; ++kg) {
                int row = m0 + s * 16 + (l & 15);
                if (row >= N_NODES) row = N_NODES - 1;
                a[s][kg] = *(const half8*)(hm16 + (size_t)row * 64 + kg * 32 + ((l >> 4) << 3));
            }
        const _Float16* pk2 = pk + 3 * 4096;
        #pragma unroll
        for (int nt = 0; nt < 4; ++nt)
            #pragma unroll
            for (int kg = 0; kg < 2; ++kg) {
                half8 b = *(const half8*)(pk2 + ((nt * 2 + kg) * 64 + l) * 8);
                acc[0][nt] = __builtin_amdgcn_mfma_f32_16x16x32_f16(a[0][kg], b, acc[0][nt], 0, 0, 0);
                acc[1][nt] = __builtin_amdgcn_mfma_f32_16x16x32_f16(a[1][kg], b, acc[1][nt], 0, 0, 0);
            }
    }

    float a1n[4], bcn[4];
    #pragma unroll
    for (int nt = 0; nt < 4; ++nt) {
        int n = nt * 16 + col;
        a1n[nt] = ab1[n];
        bcn[nt] = bcomb[n];
    }
    #pragma unroll
    for (int s = 0; s < 2; ++s)
        #pragma unroll
        for (int r = 0; r < 4; ++r) {
            int row = ((l >> 4) << 2) + r;
            int m = m0 + s * 16 + row;
            int dg = (m < N_NODES) ? (off[m + 1] - off[m]) : 0;
            #pragma unroll
            for (int nt = 0; nt < 4; ++nt) {
                int n = nt * 16 + col;
                float v = acc[s][nt][r] + a1n[nt] + ((dg > 0) ? bcn[nt] : 0.f);
                v = fmaxf(v, 0.f);
                lsh[w][s][row][n ^ ((row & 7) << 3)] = (_Float16)v;
            }
        }
    __syncthreads();

    f32x4 acc2[2][4];
    #pragma unroll
    for (int s = 0; s < 2; ++s)
        #pragma unroll
        for (int nt = 0; nt < 4; ++nt) acc2[s][nt] = z;
    {
        half8 a[2][2];
        #pragma unroll
        for (int s = 0; s < 2; ++s)
            #pragma unroll
            for (int kg = 0; kg < 2; ++kg) {
                int rr = l & 15;
                int c0 = (kg * 32 + ((l >> 4) << 3)) ^ ((rr & 7) << 3);
                a[s][kg] = *(const half8*)&lsh[w][s][rr][c0];
            }
        const _Float16* pk3 = pk + 4 * 4096;
        #pragma unroll
        for (int nt = 0; nt < 4; ++nt)
            #pragma unroll
            for (int kg = 0; kg < 2; ++kg) {
                half8 b = *(const half8*)(pk3 + ((nt * 2 + kg) * 64 + l) * 8);
                acc2[0][nt] = __builtin_amdgcn_mfma_f32_16x16x32_f16(a[0][kg], b, acc2[0][nt], 0, 0, 0);
                acc2[1][nt] = __builtin_amdgcn_mfma_f32_16x16x32_f16(a[1][kg], b, acc2[1][nt], 0, 0, 0);
            }
    }

    float a2n[4];
    #pragma unroll
    for (int nt = 0; nt < 4; ++nt) a2n[nt] = ab2[nt * 16 + col];
    #pragma unroll
    for (int s = 0; s < 2; ++s)
        #pragma unroll
        for (int r = 0; r < 4; ++r) {
            int m = m0 + s * 16 + ((l >> 4) << 2) + r;
            if (m >= N_NODES) continue;
            #pragma unroll
            for (int nt = 0; nt < 4; ++nt)
                out[(size_t)m * 64 + nt * 16 + col] = acc2[s][nt][r] + a2n[nt];
        }
}

extern "C" void kernel_launch(void* const* d_in, const int* in_sizes, int n_in,
                              void* d_out, int out_size, void* d_ws, size_t ws_size,
                              hipStream_t stream) {
    const float* x   = (const float*)d_in[0];
    const int*   ei  = (const int*)d_in[1];
    const int*   ej  = ((const int*)d_in[1]) + N_EDGES;
    const float* pos = (const float*)d_in[2];
    const float* mw1 = (const float*)d_in[3];
    const float* mb1 = (const float*)d_in[4];
    const float* mw2 = (const float*)d_in[5];
    const float* mb2 = (const float*)d_in[6];
    const float* aw1 = (const float*)d_in[7];
    const float* ab1 = (const float*)d_in[8];
    const float* aw2 = (const float*)d_in[9];
    const float* ab2 = (const float*)d_in[10];

    char* ws = (char*)d_ws;
    int*       off    = (int*)(ws + WS_OFF);
    int*       pcur   = (int*)(ws + WS_PCUR);
    int*       sj     = (int*)(ws + WS_SJ);
    float*     bcomb  = (float*)(ws + WS_BCOMB);
    _Float16*  pk     = (_Float16*)(ws + WS_PK);
    _Float16*  Q16    = (_Float16*)(ws + WS_Q);
    int*       binned = (int*)(ws + WS_BIN);
    _Float16*  hm16   = (_Float16*)(ws + WS_HM16);
    float*     out    = (float*)d_out;

    hipLaunchKernelGGL(k_setup,  dim3(6), dim3(256), 0, stream,
                       mw1, mw2, mb2, aw1, aw2, pk, bcomb, pcur);
    hipLaunchKernelGGL(k_binpre, dim3(NBB + NBT), dim3(256), 0, stream,
                       ei, ej, pcur, binned, x, pos, mw1, mb1, pk, out, Q16);
    hipLaunchKernelGGL(k_fill3s, dim3(NPART), dim3(256), 0, stream,
                       binned, pcur, off, sj);
    hipLaunchKernelGGL(k_c1,     dim3((N_NODES + 3) / 4), dim3(256), 0, stream,
                       Q16, off, sj, out, hm16);
    hipLaunchKernelGGL(k_c2,     dim3(NBT), dim3(256), 0, stream,
                       x, hm16, pk, ab1, bcomb, ab2, off, out);
}